// Round 1
// baseline (883.371 us; speedup 1.0000x reference)
//
#include <hip/hip_runtime.h>

#define NN 4096
#define FF 64
#define OO 64
#define KK 5
#define BB 8
#define CD (BB * KK * OO) /* 2560 */

typedef unsigned short bf16_t;
typedef __attribute__((ext_vector_type(8))) short short8;
typedef __attribute__((ext_vector_type(4))) float floatx4;

__device__ __forceinline__ unsigned short f2bf(float x) {
  unsigned int u = __float_as_uint(x);
  return (unsigned short)((u + 0x7fffu + ((u >> 16) & 1u)) >> 16); // RNE
}
__device__ __forceinline__ bool is_nan(float x) {
  return (__float_as_uint(x) & 0x7fffffffu) > 0x7f800000u; // immune to fast-math
}
__device__ __forceinline__ void gld16(const void* g, void* l) {
  __builtin_amdgcn_global_load_lds(
      (__attribute__((address_space(1))) const unsigned int*)g,
      (__attribute__((address_space(3))) unsigned int*)l, 16, 0, 0);
}

// ---------------- prep: var = exp(sigma), ivar, W^2 tables ----------------
__global__ __launch_bounds__(256) void prep_kernel(
    const float* __restrict__ W, const float* __restrict__ sigma,
    float* __restrict__ W2t, float* __restrict__ varr, float* __restrict__ ivarr) {
  int t = blockIdx.x * 256 + threadIdx.x;
  if (t < FF * OO) { float w = W[t]; W2t[t] = w * w; }
  if (t < KK * FF) { float v = expf(sigma[t]); varr[t] = v; ivarr[t] = 1.0f / v; }
}

// ---------------- f32 -> bf16 cast (shift, A2) ----------------
__global__ __launch_bounds__(256) void cast_bf16_kernel(
    const float* __restrict__ src, bf16_t* __restrict__ dst, int n) {
  int i = (blockIdx.x * 256 + threadIdx.x) * 8;
  if (i + 8 > n) return;
  float4 a = *(const float4*)(src + i);
  float4 b = *(const float4*)(src + i + 4);
  union { unsigned short h[8]; uint4 v; } r;
  r.h[0] = f2bf(a.x); r.h[1] = f2bf(a.y); r.h[2] = f2bf(a.z); r.h[3] = f2bf(a.w);
  r.h[4] = f2bf(b.x); r.h[5] = f2bf(b.y); r.h[6] = f2bf(b.z); r.h[7] = f2bf(b.w);
  *(uint4*)(dst + i) = r.v;
}

// ---------------- stage 1: TXT/TCT (transposed, bf16) + gamma ----------------
// block = (b, 64-row n-tile); lanes = n, waves split the o dimension (16 o each).
__global__ __launch_bounds__(256) void stage1_kernel(
    const float* __restrict__ feat,  // [B,N,F]
    const float* __restrict__ W,     // [F,O]
    const float* __restrict__ pi,    // [K]
    const float* __restrict__ mu,    // [K,F]
    const float* __restrict__ varr,  // [K,F]
    const float* __restrict__ ivarr, // [K,F]
    const float* __restrict__ W2t,   // [F,O]
    bf16_t* __restrict__ TXT,        // [CD,N]
    bf16_t* __restrict__ TCT,        // [CD,N]
    float* __restrict__ gamma)       // [B,K,N]
{
  int tid = threadIdx.x;
  int b = blockIdx.x >> 6;
  int n0 = (blockIdx.x & 63) << 6;
  int wave = tid >> 6, lane = tid & 63;

  // load this lane's feature row; split into sanitized value + nan mask (as float)
  float fvs[FF];   // NaN -> 0
  float nanf[FF];  // NaN -> 1.0 else 0.0
  const float* frow = feat + ((size_t)(b * NN) + n0 + lane) * FF;
#pragma unroll
  for (int f = 0; f < FF; f += 4) {
    float4 v4 = *(const float4*)(frow + f);
    float vv0 = v4.x, vv1 = v4.y, vv2 = v4.z, vv3 = v4.w;
    bool n0b = is_nan(vv0), n1b = is_nan(vv1), n2b = is_nan(vv2), n3b = is_nan(vv3);
    fvs[f + 0] = n0b ? 0.f : vv0; nanf[f + 0] = n0b ? 1.f : 0.f;
    fvs[f + 1] = n1b ? 0.f : vv1; nanf[f + 1] = n1b ? 1.f : 0.f;
    fvs[f + 2] = n2b ? 0.f : vv2; nanf[f + 2] = n2b ? 1.f : 0.f;
    fvs[f + 3] = n3b ? 0.f : vv3; nanf[f + 3] = n3b ? 1.f : 0.f;
  }

  // ---- responsibilities (wave 0 only; k-constant terms cancel in softmax) ----
  if (wave == 0) {
    float s[KK] = {0.f, 0.f, 0.f, 0.f, 0.f};
#pragma unroll
    for (int f = 0; f < FF; ++f) {
#pragma unroll
      for (int k = 0; k < KK; ++k) {
        float d0 = fvs[f] - mu[k * FF + f];
        float d = fmaf(-nanf[f], d0, d0); // 0 where NaN
        s[k] = fmaf(d * d, ivarr[k * FF + f], s[k]);
      }
    }
    float l[KK], mx = -3.0e38f;
#pragma unroll
    for (int k = 0; k < KK; ++k) { l[k] = pi[k] - 0.5f * s[k]; mx = fmaxf(mx, l[k]); }
    float e[KK], sum = 0.f;
#pragma unroll
    for (int k = 0; k < KK; ++k) { e[k] = expf(l[k] - mx); sum += e[k]; }
    float inv = 1.0f / sum;
#pragma unroll
    for (int k = 0; k < KK; ++k)
      gamma[(size_t)(b * KK + k) * NN + n0 + lane] = e[k] * inv;
  }

  // ---- tx/tc: tx[k,o] = sum_f fvs*W + sum_f nan*mu*W ; tc[k,o] = sum_f nan*var*W2 ----
#pragma unroll 1
  for (int oi = 0; oi < 16; ++oi) {
    int o = wave * 16 + oi;
    float txf = 0.f;
    float txc[KK] = {0.f, 0.f, 0.f, 0.f, 0.f};
    float tcc[KK] = {0.f, 0.f, 0.f, 0.f, 0.f};
#pragma unroll
    for (int f = 0; f < FF; ++f) {
      float w = W[f * OO + o];   // wave-uniform -> scalar load
      float w2 = W2t[f * OO + o];
      txf = fmaf(fvs[f], w, txf);
      float t = nanf[f] * w;
      float u = nanf[f] * w2;
#pragma unroll
      for (int k = 0; k < KK; ++k) {
        txc[k] = fmaf(t, mu[k * FF + f], txc[k]);
        tcc[k] = fmaf(u, varr[k * FF + f], tcc[k]);
      }
    }
#pragma unroll
    for (int k = 0; k < KK; ++k) {
      size_t c = (size_t)(b * KK + k) * OO + o;
      TXT[c * NN + n0 + lane] = f2bf(txf + txc[k]); // coalesced 128B rows
      TCT[c * NN + n0 + lane] = f2bf(tcc[k]);
    }
  }
}

// ---------------- GEMM: C[m][c] = sum_k A[m][k]*BT[c][k]  (m97 structure) ----------------
// A: [4096][4096] bf16, BT: [2560][4096] bf16, C: [4096][2560] f32.
// blockIdx.y selects (shift,TXT,cx) vs (A2,TCT,cc).
__global__ __launch_bounds__(256) void gemm_bt_kernel(
    const bf16_t* __restrict__ A0, const bf16_t* __restrict__ B0, float* __restrict__ C0,
    const bf16_t* __restrict__ A1, const bf16_t* __restrict__ B1, float* __restrict__ C1) {
  __shared__ bf16_t As[128 * 64]; // [m][k] contiguous (global_load_lds order)
  __shared__ bf16_t Bs[128 * 64]; // [c][k]
  const bf16_t* A = blockIdx.y ? A1 : A0;
  const bf16_t* B = blockIdx.y ? B1 : B0;
  float* C = blockIdx.y ? C1 : C0;

  int bid = blockIdx.x;
  int tile_m = bid / 20;  // 32 tiles of 128 rows
  int tile_c = bid % 20;  // 20 tiles of 128 cols

  int tid = threadIdx.x;
  int wave = tid >> 6, lane = tid & 63;
  int wm = wave >> 1, wc = wave & 1; // 2x2 wave grid, 64x64 per wave

  // staging: wave w loads rows w*32..w*32+31 of each tile, 4 gld16 per operand
  int srow = wave * 32 + (lane >> 3);
  int scol = (lane & 7) * 8;
  const bf16_t* Ag = A + (size_t)(tile_m * 128 + srow) * NN + scol;
  const bf16_t* Bg = B + (size_t)(tile_c * 128 + srow) * NN + scol;
  bf16_t* AsW = &As[(wave * 32) * 64];
  bf16_t* BsW = &Bs[(wave * 32) * 64];

  floatx4 acc[4][4];
#pragma unroll
  for (int i = 0; i < 4; ++i)
#pragma unroll
    for (int j = 0; j < 4; ++j) acc[i][j] = (floatx4){0.f, 0.f, 0.f, 0.f};

  int ml = lane & 15;
  int q = lane >> 4;

#pragma unroll 1
  for (int kt = 0; kt < 64; ++kt) {
    int k0 = kt * 64;
    __syncthreads();
#pragma unroll
    for (int i = 0; i < 4; ++i) {
      gld16(Ag + (size_t)(i * 8) * NN + k0, AsW + (i * 8) * 64);
      gld16(Bg + (size_t)(i * 8) * NN + k0, BsW + (i * 8) * 64);
    }
    __syncthreads(); // compiler drains vmcnt(0) before barrier
#pragma unroll
    for (int ks = 0; ks < 2; ++ks) {
      int ko = ks * 32 + q * 8;
      short8 a[4], bb[4];
#pragma unroll
      for (int i = 0; i < 4; ++i)
        a[i] = *(const short8*)&As[(wm * 64 + i * 16 + ml) * 64 + ko];
#pragma unroll
      for (int j = 0; j < 4; ++j)
        bb[j] = *(const short8*)&Bs[(wc * 64 + j * 16 + ml) * 64 + ko];
#pragma unroll
      for (int i = 0; i < 4; ++i)
#pragma unroll
        for (int j = 0; j < 4; ++j)
          acc[i][j] = __builtin_amdgcn_mfma_f32_16x16x32_bf16(a[i], bb[j], acc[i][j], 0, 0, 0);
    }
  }

  // epilogue: C/D layout col=lane&15, row=quad*4+reg (m89/m91-verified)
  int colb = tile_c * 128 + wc * 64 + ml;
#pragma unroll
  for (int i = 0; i < 4; ++i) {
    int mrow = tile_m * 128 + wm * 64 + i * 16 + q * 4;
#pragma unroll
    for (int j = 0; j < 4; ++j)
#pragma unroll
      for (int r = 0; r < 4; ++r)
        C[(size_t)(mrow + r) * CD + colb + j * 16] = acc[i][j][r];
  }
}

// ---------------- epilogue: ex_relu + gamma-weighted k-sum ----------------
__global__ __launch_bounds__(256) void epilogue_kernel(
    const float* __restrict__ cx, const float* __restrict__ cc,
    const float* __restrict__ gamma, float* __restrict__ out) {
  int t = blockIdx.x * 256 + threadIdx.x; // t = b*2^18 + n*64 + o
  int o = t & 63;
  int n = (t >> 6) & (NN - 1);
  int b = t >> 18;
  float sum = 0.f;
#pragma unroll
  for (int k = 0; k < KK; ++k) {
    size_t idx = (size_t)n * CD + (size_t)((b * KK + k) * OO) + o;
    float m = cx[idx];
    float v = cc[idx];
    float g = gamma[(size_t)(b * KK + k) * NN + n];
    float sd = sqrtf(fmaxf(v, 0.f));
    float z = m / (sd > 0.f ? sd : 1.f);
    float pdf = expf(-0.5f * z * z) * 0.3989422804014327f;
    float cdf = 0.5f * (1.f + erff(z * 0.7071067811865476f));
    float ex = sd > 0.f ? fmaf(m, cdf, sd * pdf) : fmaxf(m, 0.f);
    sum = fmaf(g, ex, sum);
  }
  out[t] = sum;
}

extern "C" void kernel_launch(void* const* d_in, const int* in_sizes, int n_in,
                              void* d_out, int out_size, void* d_ws, size_t ws_size,
                              hipStream_t stream) {
  const float* shift = (const float*)d_in[0];
  const float* A2    = (const float*)d_in[1];
  const float* feat  = (const float*)d_in[2];
  const float* W     = (const float*)d_in[3];
  const float* pi    = (const float*)d_in[4];
  const float* mu    = (const float*)d_in[5];
  const float* sigma = (const float*)d_in[6];
  float* out = (float*)d_out;

  char* ws = (char*)d_ws;
  bf16_t* shift_bf = (bf16_t*)(ws + 0);          //  33,554,432 B
  bf16_t* A2_bf    = (bf16_t*)(ws + 33554432);   //  33,554,432 B
  bf16_t* TXT      = (bf16_t*)(ws + 67108864);   //  20,971,520 B
  bf16_t* TCT      = (bf16_t*)(ws + 88080384);   //  20,971,520 B
  float*  cx       = (float*) (ws + 109051904);  //  41,943,040 B
  float*  cc       = (float*) (ws + 150994944);  //  41,943,040 B
  float*  gam      = (float*) (ws + 192937984);  //     655,360 B
  float*  W2t      = (float*) (ws + 193593344);  //      16,384 B
  float*  varr     = (float*) (ws + 193609728);  //       1,280 B
  float*  ivarr    = (float*) (ws + 193611008);  //       1,280 B  (total ~184.6 MiB)

  prep_kernel<<<16, 256, 0, stream>>>(W, sigma, W2t, varr, ivarr);
  cast_bf16_kernel<<<8192, 256, 0, stream>>>(shift, shift_bf, NN * NN);
  cast_bf16_kernel<<<8192, 256, 0, stream>>>(A2, A2_bf, NN * NN);
  stage1_kernel<<<512, 256, 0, stream>>>(feat, W, pi, mu, varr, ivarr, W2t, TXT, TCT, gam);
  gemm_bt_kernel<<<dim3(640, 2), 256, 0, stream>>>(shift_bf, TXT, cx, A2_bf, TCT, cc);
  epilogue_kernel<<<8192, 256, 0, stream>>>(cx, cc, gam, out);
}

// Round 2
// 474.480 us; speedup vs baseline: 1.8618x; 1.8618x over previous
//
#include <hip/hip_runtime.h>

#define NN 4096
#define FF 64
#define OO 64
#define KK 5
#define BB 8
#define CD (BB * KK * OO) /* 2560 */

typedef unsigned short bf16_t;
typedef __attribute__((ext_vector_type(8))) short short8;
typedef __attribute__((ext_vector_type(4))) float floatx4;

__device__ __forceinline__ unsigned short f2bf(float x) {
  unsigned int u = __float_as_uint(x);
  return (unsigned short)((u + 0x7fffu + ((u >> 16) & 1u)) >> 16); // RNE
}
__device__ __forceinline__ bool is_nan(float x) {
  return (__float_as_uint(x) & 0x7fffffffu) > 0x7f800000u; // raw-bits, fast-math immune
}
__device__ __forceinline__ void gld16(const void* g, void* l) {
  __builtin_amdgcn_global_load_lds(
      (__attribute__((address_space(1))) const unsigned int*)g,
      (__attribute__((address_space(3))) unsigned int*)l, 16, 0, 0);
}

union S8 { short8 s; int4 i; uint4 u; };
union U2 { unsigned short h[4]; uint2 u; };

// ---------------- prep: ivar, bf16 tables (mu, var, W^T, (W^2)^T) ----------------
__global__ __launch_bounds__(256) void prep_kernel(
    const float* __restrict__ W, const float* __restrict__ sigma,
    const float* __restrict__ mu,
    float* __restrict__ ivarr, bf16_t* __restrict__ mu_bf, bf16_t* __restrict__ var_bf,
    bf16_t* __restrict__ WTb, bf16_t* __restrict__ W2Tb) {
  int t = blockIdx.x * 256 + threadIdx.x;
  if (t < KK * FF) {
    float v = expf(sigma[t]);
    ivarr[t] = 1.0f / v;
    var_bf[t] = f2bf(v);
    mu_bf[t] = f2bf(mu[t]);
  }
  if (t < FF * OO) {
    int o = t >> 6, f = t & 63;
    float w = W[f * OO + o];
    WTb[t] = f2bf(w);       // WT[o][f]
    W2Tb[t] = f2bf(w * w);  // (W^2)T[o][f]
  }
}

// ---------------- f32 -> bf16 cast (shift, A2) ----------------
__global__ __launch_bounds__(256) void cast_bf16_kernel(
    const float* __restrict__ src, bf16_t* __restrict__ dst, int n) {
  int i = (blockIdx.x * 256 + threadIdx.x) * 8;
  if (i + 8 > n) return;
  float4 a = *(const float4*)(src + i);
  float4 b = *(const float4*)(src + i + 4);
  union { unsigned short h[8]; uint4 v; } r;
  r.h[0] = f2bf(a.x); r.h[1] = f2bf(a.y); r.h[2] = f2bf(a.z); r.h[3] = f2bf(a.w);
  r.h[4] = f2bf(b.x); r.h[5] = f2bf(b.y); r.h[6] = f2bf(b.z); r.h[7] = f2bf(b.w);
  *(uint4*)(dst + i) = r.v;
}

// ---------------- stage 1 (MFMA): TXT/TCT (bf16, transposed) + gamma ----------------
// Block = (b, 64-row n-tile). Wave w owns rows [w*16, w*16+16). No LDS, no barriers.
// tx = mean_mat @ W, tc = var_mat @ W^2 via 16x16x32 bf16 MFMA; fragments built
// in-register with bfi(nanmask, mu, feat).
__global__ __launch_bounds__(256) void stage1_kernel(
    const float* __restrict__ feat,   // [B,N,F]
    const float* __restrict__ pi,     // [K]
    const float* __restrict__ mu,     // [K,F] f32
    const float* __restrict__ ivarr,  // [K,F] f32
    const bf16_t* __restrict__ mu_bf, // [K,F]
    const bf16_t* __restrict__ var_bf,// [K,F]
    const bf16_t* __restrict__ WTb,   // [O,F]
    const bf16_t* __restrict__ W2Tb,  // [O,F]
    bf16_t* __restrict__ TXT,         // [CD,N]
    bf16_t* __restrict__ TCT,         // [CD,N]
    float* __restrict__ gamma)        // [B,K,N]
{
  int tid = threadIdx.x;
  int b = blockIdx.x >> 6;
  int n0 = (blockIdx.x & 63) << 6;
  int w = tid >> 6, lane = tid & 63;
  int m = lane & 15, q = lane >> 4;
  int row = n0 + w * 16 + m; // this lane's n-row for both gamma and A-fragments
  const float* frow = feat + ((size_t)b * NN + row) * FF;

  // ---- gamma: 4 lanes per row, lane covers f in [q*16, q*16+16), shfl-reduce ----
  {
    float s[KK] = {0.f, 0.f, 0.f, 0.f, 0.f};
#pragma unroll
    for (int fi = 0; fi < 16; fi += 4) {
      int f = q * 16 + fi;
      float4 v4 = *(const float4*)(frow + f);
      float vv[4] = {v4.x, v4.y, v4.z, v4.w};
#pragma unroll
      for (int e = 0; e < 4; ++e) {
        bool nb = is_nan(vv[e]);
        float x = nb ? 0.f : vv[e];
#pragma unroll
        for (int k = 0; k < KK; ++k) {
          float d = nb ? 0.f : (x - mu[k * FF + f + e]);
          s[k] = fmaf(d * d, ivarr[k * FF + f + e], s[k]);
        }
      }
    }
#pragma unroll
    for (int k = 0; k < KK; ++k) {
      s[k] += __shfl_xor(s[k], 16);
      s[k] += __shfl_xor(s[k], 32);
    }
    float l[KK], mx = -3.0e38f;
#pragma unroll
    for (int k = 0; k < KK; ++k) { l[k] = pi[k] - 0.5f * s[k]; mx = fmaxf(mx, l[k]); }
    float ek[KK], sum = 0.f;
#pragma unroll
    for (int k = 0; k < KK; ++k) { ek[k] = expf(l[k] - mx); sum += ek[k]; }
    float inv = 1.0f / sum;
    if (q == 0) {
#pragma unroll
      for (int k = 0; k < KK; ++k)
        gamma[(size_t)(b * KK + k) * NN + row] = ek[k] * inv; // 16 consecutive f32
    }
  }

  // ---- A-fragments: sanitized feat (bf16) + NaN mask, ks=0/1 (f = ks*32+q*8 ..+8) ----
  S8 fvs[2], msk[2];
#pragma unroll
  for (int ks = 0; ks < 2; ++ks) {
    float4 a4 = *(const float4*)(frow + ks * 32 + q * 8);
    float4 b4 = *(const float4*)(frow + ks * 32 + q * 8 + 4);
    float vv[8] = {a4.x, a4.y, a4.z, a4.w, b4.x, b4.y, b4.z, b4.w};
#pragma unroll
    for (int e = 0; e < 8; ++e) {
      bool nb = is_nan(vv[e]);
      fvs[ks].s[e] = (short)(nb ? 0 : f2bf(vv[e]));
      msk[ks].s[e] = (short)(nb ? 0xFFFF : 0);
    }
  }

  // ---- W fragments (register-resident, reused across all k) ----
  short8 wf[4][2], w2f[4][2];
#pragma unroll
  for (int ot = 0; ot < 4; ++ot)
#pragma unroll
    for (int ks = 0; ks < 2; ++ks) {
      int off = (ot * 16 + m) * FF + ks * 32 + q * 8;
      wf[ot][ks] = *(const short8*)(WTb + off);
      w2f[ot][ks] = *(const short8*)(W2Tb + off);
    }

  // ---- per-component MFMA + store ----
#pragma unroll
  for (int k = 0; k < KK; ++k) {
    S8 mean[2], varm[2];
#pragma unroll
    for (int ks = 0; ks < 2; ++ks) {
      S8 mf, vf;
      mf.s = *(const short8*)(mu_bf + k * FF + ks * 32 + q * 8);  // broadcast
      vf.s = *(const short8*)(var_bf + k * FF + ks * 32 + q * 8);
      mean[ks].i.x = (msk[ks].i.x & mf.i.x) | (~msk[ks].i.x & fvs[ks].i.x);
      mean[ks].i.y = (msk[ks].i.y & mf.i.y) | (~msk[ks].i.y & fvs[ks].i.y);
      mean[ks].i.z = (msk[ks].i.z & mf.i.z) | (~msk[ks].i.z & fvs[ks].i.z);
      mean[ks].i.w = (msk[ks].i.w & mf.i.w) | (~msk[ks].i.w & fvs[ks].i.w);
      varm[ks].i.x = msk[ks].i.x & vf.i.x;
      varm[ks].i.y = msk[ks].i.y & vf.i.y;
      varm[ks].i.z = msk[ks].i.z & vf.i.z;
      varm[ks].i.w = msk[ks].i.w & vf.i.w;
    }
#pragma unroll
    for (int ot = 0; ot < 4; ++ot) {
      floatx4 z = (floatx4){0.f, 0.f, 0.f, 0.f};
      floatx4 tx = __builtin_amdgcn_mfma_f32_16x16x32_bf16(mean[0].s, wf[ot][0], z, 0, 0, 0);
      tx = __builtin_amdgcn_mfma_f32_16x16x32_bf16(mean[1].s, wf[ot][1], tx, 0, 0, 0);
      floatx4 tc = __builtin_amdgcn_mfma_f32_16x16x32_bf16(varm[0].s, w2f[ot][0], z, 0, 0, 0);
      tc = __builtin_amdgcn_mfma_f32_16x16x32_bf16(varm[1].s, w2f[ot][1], tc, 0, 0, 0);
      // C/D layout: col(o)=lane&15 from B-operand, row(n)=q*4+r from A-operand
      int o = ot * 16 + m;
      size_t c = (size_t)((b * KK + k) * OO + o);
      size_t addr = c * NN + (size_t)(n0 + w * 16 + q * 4);
      U2 px, pc;
#pragma unroll
      for (int r = 0; r < 4; ++r) { px.h[r] = f2bf(tx[r]); pc.h[r] = f2bf(tc[r]); }
      *(uint2*)(TXT + addr) = px.u;
      *(uint2*)(TCT + addr) = pc.u;
    }
  }
}

// ---------------- GEMM: C[m][c] = sum_k A[m][k]*BT[c][k]  (m97 structure) ----------------
__global__ __launch_bounds__(256) void gemm_bt_kernel(
    const bf16_t* __restrict__ A0, const bf16_t* __restrict__ B0, float* __restrict__ C0,
    const bf16_t* __restrict__ A1, const bf16_t* __restrict__ B1, float* __restrict__ C1) {
  __shared__ bf16_t As[128 * 64]; // [m][k] contiguous (global_load_lds order)
  __shared__ bf16_t Bs[128 * 64]; // [c][k]
  const bf16_t* A = blockIdx.y ? A1 : A0;
  const bf16_t* B = blockIdx.y ? B1 : B0;
  float* C = blockIdx.y ? C1 : C0;

  int bid = blockIdx.x;
  int tile_m = bid / 20;
  int tile_c = bid % 20;

  int tid = threadIdx.x;
  int wave = tid >> 6, lane = tid & 63;
  int wm = wave >> 1, wc = wave & 1;

  int srow = wave * 32 + (lane >> 3);
  int scol = (lane & 7) * 8;
  const bf16_t* Ag = A + (size_t)(tile_m * 128 + srow) * NN + scol;
  const bf16_t* Bg = B + (size_t)(tile_c * 128 + srow) * NN + scol;
  bf16_t* AsW = &As[(wave * 32) * 64];
  bf16_t* BsW = &Bs[(wave * 32) * 64];

  floatx4 acc[4][4];
#pragma unroll
  for (int i = 0; i < 4; ++i)
#pragma unroll
    for (int j = 0; j < 4; ++j) acc[i][j] = (floatx4){0.f, 0.f, 0.f, 0.f};

  int ml = lane & 15;
  int q = lane >> 4;

#pragma unroll 1
  for (int kt = 0; kt < 64; ++kt) {
    int k0 = kt * 64;
    __syncthreads();
#pragma unroll
    for (int i = 0; i < 4; ++i) {
      gld16(Ag + (size_t)(i * 8) * NN + k0, AsW + (i * 8) * 64);
      gld16(Bg + (size_t)(i * 8) * NN + k0, BsW + (i * 8) * 64);
    }
    __syncthreads();
#pragma unroll
    for (int ks = 0; ks < 2; ++ks) {
      int ko = ks * 32 + q * 8;
      short8 a[4], bb[4];
#pragma unroll
      for (int i = 0; i < 4; ++i)
        a[i] = *(const short8*)&As[(wm * 64 + i * 16 + ml) * 64 + ko];
#pragma unroll
      for (int j = 0; j < 4; ++j)
        bb[j] = *(const short8*)&Bs[(wc * 64 + j * 16 + ml) * 64 + ko];
#pragma unroll
      for (int i = 0; i < 4; ++i)
#pragma unroll
        for (int j = 0; j < 4; ++j)
          acc[i][j] = __builtin_amdgcn_mfma_f32_16x16x32_bf16(a[i], bb[j], acc[i][j], 0, 0, 0);
    }
  }

  int colb = tile_c * 128 + wc * 64 + ml;
#pragma unroll
  for (int i = 0; i < 4; ++i) {
    int mrow = tile_m * 128 + wm * 64 + i * 16 + q * 4;
#pragma unroll
    for (int j = 0; j < 4; ++j)
#pragma unroll
      for (int r = 0; r < 4; ++r)
        C[(size_t)(mrow + r) * CD + colb + j * 16] = acc[i][j][r];
  }
}

// ---------------- epilogue: ex_relu + gamma-weighted k-sum ----------------
__global__ __launch_bounds__(256) void epilogue_kernel(
    const float* __restrict__ cx, const float* __restrict__ cc,
    const float* __restrict__ gamma, float* __restrict__ out) {
  int t = blockIdx.x * 256 + threadIdx.x; // t = b*2^18 + n*64 + o
  int o = t & 63;
  int n = (t >> 6) & (NN - 1);
  int b = t >> 18;
  float sum = 0.f;
#pragma unroll
  for (int k = 0; k < KK; ++k) {
    size_t idx = (size_t)n * CD + (size_t)((b * KK + k) * OO) + o;
    float m = cx[idx];
    float v = cc[idx];
    float g = gamma[(size_t)(b * KK + k) * NN + n];
    float sd = sqrtf(fmaxf(v, 0.f));
    float z = m / (sd > 0.f ? sd : 1.f);
    float pdf = expf(-0.5f * z * z) * 0.3989422804014327f;
    float cdf = 0.5f * (1.f + erff(z * 0.7071067811865476f));
    float ex = sd > 0.f ? fmaf(m, cdf, sd * pdf) : fmaxf(m, 0.f);
    sum = fmaf(g, ex, sum);
  }
  out[t] = sum;
}

extern "C" void kernel_launch(void* const* d_in, const int* in_sizes, int n_in,
                              void* d_out, int out_size, void* d_ws, size_t ws_size,
                              hipStream_t stream) {
  const float* shift = (const float*)d_in[0];
  const float* A2    = (const float*)d_in[1];
  const float* feat  = (const float*)d_in[2];
  const float* W     = (const float*)d_in[3];
  const float* pi    = (const float*)d_in[4];
  const float* mu    = (const float*)d_in[5];
  const float* sigma = (const float*)d_in[6];
  float* out = (float*)d_out;

  char* ws = (char*)d_ws;
  bf16_t* shift_bf = (bf16_t*)(ws + 0);          //  33,554,432 B
  bf16_t* A2_bf    = (bf16_t*)(ws + 33554432);   //  33,554,432 B
  bf16_t* TXT      = (bf16_t*)(ws + 67108864);   //  20,971,520 B
  bf16_t* TCT      = (bf16_t*)(ws + 88080384);   //  20,971,520 B
  float*  cx       = (float*) (ws + 109051904);  //  41,943,040 B
  float*  cc       = (float*) (ws + 150994944);  //  41,943,040 B
  float*  gam      = (float*) (ws + 192937984);  //     655,360 B
  float*  ivarr    = (float*) (ws + 193593344);  //       1,280 B
  bf16_t* mu_bf    = (bf16_t*)(ws + 193594624);  //         640 B
  bf16_t* var_bf   = (bf16_t*)(ws + 193595264);  //         640 B
  bf16_t* WTb      = (bf16_t*)(ws + 193595904);  //       8,192 B
  bf16_t* W2Tb     = (bf16_t*)(ws + 193604096);  //       8,192 B (end ~184.6 MiB)

  prep_kernel<<<16, 256, 0, stream>>>(W, sigma, mu, ivarr, mu_bf, var_bf, WTb, W2Tb);
  cast_bf16_kernel<<<8192, 256, 0, stream>>>(shift, shift_bf, NN * NN);
  cast_bf16_kernel<<<8192, 256, 0, stream>>>(A2, A2_bf, NN * NN);
  stage1_kernel<<<512, 256, 0, stream>>>(feat, pi, mu, ivarr, mu_bf, var_bf, WTb, W2Tb,
                                         TXT, TCT, gam);
  gemm_bt_kernel<<<dim3(640, 2), 256, 0, stream>>>(shift_bf, TXT, cx, A2_bf, TCT, cc);
  epilogue_kernel<<<8192, 256, 0, stream>>>(cx, cc, gam, out);
}

// Round 3
// 407.893 us; speedup vs baseline: 2.1657x; 1.1632x over previous
//
#include <hip/hip_runtime.h>

#define NN 4096
#define FF 64
#define OO 64
#define KK 5
#define BB 8
#define CD (BB * KK * OO) /* 2560 */

typedef unsigned short bf16_t;
typedef __attribute__((ext_vector_type(8))) short short8;
typedef __attribute__((ext_vector_type(4))) float floatx4;

__device__ __forceinline__ unsigned short f2bf(float x) {
  unsigned int u = __float_as_uint(x);
  return (unsigned short)((u + 0x7fffu + ((u >> 16) & 1u)) >> 16); // RNE
}
__device__ __forceinline__ float bf2f(unsigned short h) {
  return __uint_as_float(((unsigned int)h) << 16);
}
__device__ __forceinline__ bool is_nan(float x) {
  return (__float_as_uint(x) & 0x7fffffffu) > 0x7f800000u; // raw-bits, fast-math immune
}
__device__ __forceinline__ void gld16(const void* g, void* l) {
  __builtin_amdgcn_global_load_lds(
      (__attribute__((address_space(1))) const unsigned int*)g,
      (__attribute__((address_space(3))) unsigned int*)l, 16, 0, 0);
}

union S8 { short8 s; int4 i; uint4 u; };
union U2 { unsigned short h[4]; uint2 u; };

// ---------------- prep: ivar, bf16 tables (mu, var, W^T, (W^2)^T) ----------------
__global__ __launch_bounds__(256) void prep_kernel(
    const float* __restrict__ W, const float* __restrict__ sigma,
    const float* __restrict__ mu,
    float* __restrict__ ivarr, bf16_t* __restrict__ mu_bf, bf16_t* __restrict__ var_bf,
    bf16_t* __restrict__ WTb, bf16_t* __restrict__ W2Tb) {
  int t = blockIdx.x * 256 + threadIdx.x;
  if (t < KK * FF) {
    float v = expf(sigma[t]);
    ivarr[t] = 1.0f / v;
    var_bf[t] = f2bf(v);
    mu_bf[t] = f2bf(mu[t]);
  }
  if (t < FF * OO) {
    int o = t >> 6, f = t & 63;
    float w = W[f * OO + o];
    WTb[t] = f2bf(w);       // WT[o][f]
    W2Tb[t] = f2bf(w * w);  // (W^2)T[o][f]
  }
}

// ---------------- f32 -> bf16 cast (shift, A2) ----------------
__global__ __launch_bounds__(256) void cast_bf16_kernel(
    const float* __restrict__ src, bf16_t* __restrict__ dst, int n) {
  int i = (blockIdx.x * 256 + threadIdx.x) * 8;
  if (i + 8 > n) return;
  float4 a = *(const float4*)(src + i);
  float4 b = *(const float4*)(src + i + 4);
  union { unsigned short h[8]; uint4 v; } r;
  r.h[0] = f2bf(a.x); r.h[1] = f2bf(a.y); r.h[2] = f2bf(a.z); r.h[3] = f2bf(a.w);
  r.h[4] = f2bf(b.x); r.h[5] = f2bf(b.y); r.h[6] = f2bf(b.z); r.h[7] = f2bf(b.w);
  *(uint4*)(dst + i) = r.v;
}

// ---------------- stage 1 (MFMA): TXT/TCT (bf16, transposed) + gamma ----------------
__global__ __launch_bounds__(256) void stage1_kernel(
    const float* __restrict__ feat,   // [B,N,F]
    const float* __restrict__ pi,     // [K]
    const float* __restrict__ mu,     // [K,F] f32
    const float* __restrict__ ivarr,  // [K,F] f32
    const bf16_t* __restrict__ mu_bf, // [K,F]
    const bf16_t* __restrict__ var_bf,// [K,F]
    const bf16_t* __restrict__ WTb,   // [O,F]
    const bf16_t* __restrict__ W2Tb,  // [O,F]
    bf16_t* __restrict__ TXT,         // [CD,N]
    bf16_t* __restrict__ TCT,         // [CD,N]
    float* __restrict__ gamma)        // [B,K,N]
{
  int tid = threadIdx.x;
  int b = blockIdx.x >> 6;
  int n0 = (blockIdx.x & 63) << 6;
  int w = tid >> 6, lane = tid & 63;
  int m = lane & 15, q = lane >> 4;
  int row = n0 + w * 16 + m;
  const float* frow = feat + ((size_t)b * NN + row) * FF;

  // ---- gamma: 4 lanes per row, lane covers f in [q*16, q*16+16), shfl-reduce ----
  {
    float s[KK] = {0.f, 0.f, 0.f, 0.f, 0.f};
#pragma unroll
    for (int fi = 0; fi < 16; fi += 4) {
      int f = q * 16 + fi;
      float4 v4 = *(const float4*)(frow + f);
      float vv[4] = {v4.x, v4.y, v4.z, v4.w};
#pragma unroll
      for (int e = 0; e < 4; ++e) {
        bool nb = is_nan(vv[e]);
        float x = nb ? 0.f : vv[e];
#pragma unroll
        for (int k = 0; k < KK; ++k) {
          float d = nb ? 0.f : (x - mu[k * FF + f + e]);
          s[k] = fmaf(d * d, ivarr[k * FF + f + e], s[k]);
        }
      }
    }
#pragma unroll
    for (int k = 0; k < KK; ++k) {
      s[k] += __shfl_xor(s[k], 16);
      s[k] += __shfl_xor(s[k], 32);
    }
    float l[KK], mx = -3.0e38f;
#pragma unroll
    for (int k = 0; k < KK; ++k) { l[k] = pi[k] - 0.5f * s[k]; mx = fmaxf(mx, l[k]); }
    float ek[KK], sum = 0.f;
#pragma unroll
    for (int k = 0; k < KK; ++k) { ek[k] = expf(l[k] - mx); sum += ek[k]; }
    float inv = 1.0f / sum;
    if (q == 0) {
#pragma unroll
      for (int k = 0; k < KK; ++k)
        gamma[(size_t)(b * KK + k) * NN + row] = ek[k] * inv;
    }
  }

  // ---- A-fragments: sanitized feat (bf16) + NaN mask ----
  S8 fvs[2], msk[2];
#pragma unroll
  for (int ks = 0; ks < 2; ++ks) {
    float4 a4 = *(const float4*)(frow + ks * 32 + q * 8);
    float4 b4 = *(const float4*)(frow + ks * 32 + q * 8 + 4);
    float vv[8] = {a4.x, a4.y, a4.z, a4.w, b4.x, b4.y, b4.z, b4.w};
#pragma unroll
    for (int e = 0; e < 8; ++e) {
      bool nb = is_nan(vv[e]);
      fvs[ks].s[e] = (short)(nb ? 0 : f2bf(vv[e]));
      msk[ks].s[e] = (short)(nb ? 0xFFFF : 0);
    }
  }

  // ---- W fragments (register-resident, reused across all k) ----
  short8 wf[4][2], w2f[4][2];
#pragma unroll
  for (int ot = 0; ot < 4; ++ot)
#pragma unroll
    for (int ks = 0; ks < 2; ++ks) {
      int off = (ot * 16 + m) * FF + ks * 32 + q * 8;
      wf[ot][ks] = *(const short8*)(WTb + off);
      w2f[ot][ks] = *(const short8*)(W2Tb + off);
    }

  // ---- per-component MFMA + store ----
#pragma unroll
  for (int k = 0; k < KK; ++k) {
    S8 mean[2], varm[2];
#pragma unroll
    for (int ks = 0; ks < 2; ++ks) {
      S8 mf, vf;
      mf.s = *(const short8*)(mu_bf + k * FF + ks * 32 + q * 8);
      vf.s = *(const short8*)(var_bf + k * FF + ks * 32 + q * 8);
      mean[ks].i.x = (msk[ks].i.x & mf.i.x) | (~msk[ks].i.x & fvs[ks].i.x);
      mean[ks].i.y = (msk[ks].i.y & mf.i.y) | (~msk[ks].i.y & fvs[ks].i.y);
      mean[ks].i.z = (msk[ks].i.z & mf.i.z) | (~msk[ks].i.z & fvs[ks].i.z);
      mean[ks].i.w = (msk[ks].i.w & mf.i.w) | (~msk[ks].i.w & fvs[ks].i.w);
      varm[ks].i.x = msk[ks].i.x & vf.i.x;
      varm[ks].i.y = msk[ks].i.y & vf.i.y;
      varm[ks].i.z = msk[ks].i.z & vf.i.z;
      varm[ks].i.w = msk[ks].i.w & vf.i.w;
    }
#pragma unroll
    for (int ot = 0; ot < 4; ++ot) {
      floatx4 z = (floatx4){0.f, 0.f, 0.f, 0.f};
      floatx4 tx = __builtin_amdgcn_mfma_f32_16x16x32_bf16(mean[0].s, wf[ot][0], z, 0, 0, 0);
      tx = __builtin_amdgcn_mfma_f32_16x16x32_bf16(mean[1].s, wf[ot][1], tx, 0, 0, 0);
      floatx4 tc = __builtin_amdgcn_mfma_f32_16x16x32_bf16(varm[0].s, w2f[ot][0], z, 0, 0, 0);
      tc = __builtin_amdgcn_mfma_f32_16x16x32_bf16(varm[1].s, w2f[ot][1], tc, 0, 0, 0);
      int o = ot * 16 + m;
      size_t c = (size_t)((b * KK + k) * OO + o);
      size_t addr = c * NN + (size_t)(n0 + w * 16 + q * 4);
      U2 px, pc;
#pragma unroll
      for (int r = 0; r < 4; ++r) { px.h[r] = f2bf(tx[r]); pc.h[r] = f2bf(tc[r]); }
      *(uint2*)(TXT + addr) = px.u;
      *(uint2*)(TCT + addr) = pc.u;
    }
  }
}

// ---------------- GEMM: C[m][c] = sum_k A[m][k]*BT[c][k], bf16 out ----------------
// LDS 16B-chunk XOR swizzle: phys_chunk = log_chunk ^ (row&7). Staging swizzles the
// GLOBAL source column (global_load_lds dst is fixed base+lane*16); reads swizzle
// the chunk index. Breaks the 128B-stride 16-way bank conflict -> <=2-way (free).
__global__ __launch_bounds__(256) void gemm_bt_kernel(
    const bf16_t* __restrict__ A0, const bf16_t* __restrict__ B0, bf16_t* __restrict__ C0,
    const bf16_t* __restrict__ A1, const bf16_t* __restrict__ B1, bf16_t* __restrict__ C1) {
  __shared__ bf16_t As[128 * 64];
  __shared__ bf16_t Bs[128 * 64];
  const bf16_t* A = blockIdx.y ? A1 : A0;
  const bf16_t* B = blockIdx.y ? B1 : B0;
  bf16_t* C = blockIdx.y ? C1 : C0;

  int bid = blockIdx.x;
  int tile_m = bid / 20;
  int tile_c = bid % 20;

  int tid = threadIdx.x;
  int wave = tid >> 6, lane = tid & 63;
  int wm = wave >> 1, wc = wave & 1;

  int srow = wave * 32 + (lane >> 3);
  int scol = (((lane & 7) ^ (lane >> 3)) << 3); // XOR-swizzled source chunk
  const bf16_t* Ag = A + (size_t)(tile_m * 128 + srow) * NN + scol;
  const bf16_t* Bg = B + (size_t)(tile_c * 128 + srow) * NN + scol;
  bf16_t* AsW = &As[(wave * 32) * 64];
  bf16_t* BsW = &Bs[(wave * 32) * 64];

  floatx4 acc[4][4];
#pragma unroll
  for (int i = 0; i < 4; ++i)
#pragma unroll
    for (int j = 0; j < 4; ++j) acc[i][j] = (floatx4){0.f, 0.f, 0.f, 0.f};

  int ml = lane & 15;
  int q = lane >> 4;
  int sw = ml & 7; // row&7 of every fragment row this lane touches

#pragma unroll 1
  for (int kt = 0; kt < 64; ++kt) {
    int k0 = kt * 64;
    __syncthreads();
#pragma unroll
    for (int i = 0; i < 4; ++i) {
      gld16(Ag + (size_t)(i * 8) * NN + k0, AsW + (i * 8) * 64);
      gld16(Bg + (size_t)(i * 8) * NN + k0, BsW + (i * 8) * 64);
    }
    __syncthreads();
#pragma unroll
    for (int ks = 0; ks < 2; ++ks) {
      int chunk = (((ks * 4 + q) ^ sw) << 3); // swizzled phys chunk for log ko
      short8 a[4], bb[4];
#pragma unroll
      for (int i = 0; i < 4; ++i)
        a[i] = *(const short8*)&As[(wm * 64 + i * 16 + ml) * 64 + chunk];
#pragma unroll
      for (int j = 0; j < 4; ++j)
        bb[j] = *(const short8*)&Bs[(wc * 64 + j * 16 + ml) * 64 + chunk];
#pragma unroll
      for (int i = 0; i < 4; ++i)
#pragma unroll
        for (int j = 0; j < 4; ++j)
          acc[i][j] = __builtin_amdgcn_mfma_f32_16x16x32_bf16(a[i], bb[j], acc[i][j], 0, 0, 0);
    }
  }

  int colb = tile_c * 128 + wc * 64 + ml;
#pragma unroll
  for (int i = 0; i < 4; ++i) {
    int mrow = tile_m * 128 + wm * 64 + i * 16 + q * 4;
#pragma unroll
    for (int j = 0; j < 4; ++j)
#pragma unroll
      for (int r = 0; r < 4; ++r)
        C[(size_t)(mrow + r) * CD + colb + j * 16] = f2bf(acc[i][j][r]);
  }
}

// ---------------- epilogue: ex_relu + gamma-weighted k-sum (bf16 cx/cc) ----------------
__global__ __launch_bounds__(256) void epilogue_kernel(
    const bf16_t* __restrict__ cx, const bf16_t* __restrict__ cc,
    const float* __restrict__ gamma, float* __restrict__ out) {
  int t = blockIdx.x * 256 + threadIdx.x; // t = b*2^18 + n*64 + o
  int o = t & 63;
  int n = (t >> 6) & (NN - 1);
  int b = t >> 18;
  float sum = 0.f;
#pragma unroll
  for (int k = 0; k < KK; ++k) {
    size_t idx = (size_t)n * CD + (size_t)((b * KK + k) * OO) + o;
    float m = bf2f(cx[idx]);
    float v = bf2f(cc[idx]);
    float g = gamma[(size_t)(b * KK + k) * NN + n];
    float sd = sqrtf(fmaxf(v, 0.f));
    float z = m / (sd > 0.f ? sd : 1.f);
    float pdf = expf(-0.5f * z * z) * 0.3989422804014327f;
    float cdf = 0.5f * (1.f + erff(z * 0.7071067811865476f));
    float ex = sd > 0.f ? fmaf(m, cdf, sd * pdf) : fmaxf(m, 0.f);
    sum = fmaf(g, ex, sum);
  }
  out[t] = sum;
}

extern "C" void kernel_launch(void* const* d_in, const int* in_sizes, int n_in,
                              void* d_out, int out_size, void* d_ws, size_t ws_size,
                              hipStream_t stream) {
  const float* shift = (const float*)d_in[0];
  const float* A2    = (const float*)d_in[1];
  const float* feat  = (const float*)d_in[2];
  const float* W     = (const float*)d_in[3];
  const float* pi    = (const float*)d_in[4];
  const float* mu    = (const float*)d_in[5];
  const float* sigma = (const float*)d_in[6];
  float* out = (float*)d_out;

  char* ws = (char*)d_ws;
  bf16_t* shift_bf = (bf16_t*)(ws + 0);          //  33,554,432 B
  bf16_t* A2_bf    = (bf16_t*)(ws + 33554432);   //  33,554,432 B
  bf16_t* TXT      = (bf16_t*)(ws + 67108864);   //  20,971,520 B
  bf16_t* TCT      = (bf16_t*)(ws + 88080384);   //  20,971,520 B
  bf16_t* cxb      = (bf16_t*)(ws + 109051904);  //  20,971,520 B
  bf16_t* ccb      = (bf16_t*)(ws + 130023424);  //  20,971,520 B
  float*  gam      = (float*) (ws + 150994944);  //     655,360 B
  float*  ivarr    = (float*) (ws + 151650304);  //       1,280 B
  bf16_t* mu_bf    = (bf16_t*)(ws + 151651584);  //         640 B
  bf16_t* var_bf   = (bf16_t*)(ws + 151652224);  //         640 B
  bf16_t* WTb      = (bf16_t*)(ws + 151652864);  //       8,192 B
  bf16_t* W2Tb     = (bf16_t*)(ws + 151661056);  //       8,192 B (end ~144.6 MiB)

  prep_kernel<<<16, 256, 0, stream>>>(W, sigma, mu, ivarr, mu_bf, var_bf, WTb, W2Tb);
  cast_bf16_kernel<<<8192, 256, 0, stream>>>(shift, shift_bf, NN * NN);
  cast_bf16_kernel<<<8192, 256, 0, stream>>>(A2, A2_bf, NN * NN);
  stage1_kernel<<<512, 256, 0, stream>>>(feat, pi, mu, ivarr, mu_bf, var_bf, WTb, W2Tb,
                                         TXT, TCT, gam);
  gemm_bt_kernel<<<dim3(640, 2), 256, 0, stream>>>(shift_bf, TXT, cxb, A2_bf, TCT, ccb);
  epilogue_kernel<<<8192, 256, 0, stream>>>(cxb, ccb, gam, out);
}

// Round 4
// 305.584 us; speedup vs baseline: 2.8908x; 1.3348x over previous
//
#include <hip/hip_runtime.h>

#define NN 4096
#define FF 64
#define OO 64
#define KK 5
#define BB 8

typedef unsigned short bf16_t;
typedef __attribute__((ext_vector_type(8))) short short8;
typedef __attribute__((ext_vector_type(4))) float floatx4;

__device__ __forceinline__ unsigned short f2bf(float x) {
  unsigned int u = __float_as_uint(x);
  return (unsigned short)((u + 0x7fffu + ((u >> 16) & 1u)) >> 16); // RNE
}
__device__ __forceinline__ bool is_nan(float x) {
  return (__float_as_uint(x) & 0x7fffffffu) > 0x7f800000u; // raw-bits, fast-math immune
}
__device__ __forceinline__ void gld16(const void* g, void* l) {
  __builtin_amdgcn_global_load_lds(
      (__attribute__((address_space(1))) const unsigned int*)g,
      (__attribute__((address_space(3))) unsigned int*)l, 16, 0, 0);
}

// ---------------- prep: ivar + bf16 tables W^T, E_k^T = (mu.W)^T, D_k^T = (var.W^2)^T ----------------
__global__ __launch_bounds__(256) void prep_kernel(
    const float* __restrict__ W, const float* __restrict__ sigma, const float* __restrict__ mu,
    float* __restrict__ ivarr, bf16_t* __restrict__ WTb,
    bf16_t* __restrict__ EkT, bf16_t* __restrict__ DkT) {
  int t = blockIdx.x * 256 + threadIdx.x; // grid 80*256 = 20480 = K*64*64
  if (t < KK * FF) ivarr[t] = expf(-sigma[t]);
  if (t < FF * OO) {
    int o = t >> 6, f = t & 63;
    WTb[t] = f2bf(W[f * OO + o]);
  }
  int k = t >> 12, o = (t >> 6) & 63, f = t & 63;
  if (k < KK) {
    float w = W[f * OO + o];
    EkT[t] = f2bf(mu[k * FF + f] * w);
    DkT[t] = f2bf(expf(sigma[k * FF + f]) * w * w);
  }
}

// ---------------- f32 -> bf16 cast for both shift and A2 ----------------
__global__ __launch_bounds__(256) void cast2_kernel(
    const float* __restrict__ s0, const float* __restrict__ s1,
    bf16_t* __restrict__ d0, bf16_t* __restrict__ d1) {
  int i = (blockIdx.x * 256 + threadIdx.x) * 8;
  if (i + 8 > NN * NN) return;
  float4 a = *(const float4*)(s0 + i);
  float4 b = *(const float4*)(s0 + i + 4);
  union { unsigned short h[8]; uint4 v; } r;
  r.h[0] = f2bf(a.x); r.h[1] = f2bf(a.y); r.h[2] = f2bf(a.z); r.h[3] = f2bf(a.w);
  r.h[4] = f2bf(b.x); r.h[5] = f2bf(b.y); r.h[6] = f2bf(b.z); r.h[7] = f2bf(b.w);
  *(uint4*)(d0 + i) = r.v;
  a = *(const float4*)(s1 + i);
  b = *(const float4*)(s1 + i + 4);
  r.h[0] = f2bf(a.x); r.h[1] = f2bf(a.y); r.h[2] = f2bf(a.z); r.h[3] = f2bf(a.w);
  r.h[4] = f2bf(b.x); r.h[5] = f2bf(b.y); r.h[6] = f2bf(b.z); r.h[7] = f2bf(b.w);
  *(uint4*)(d1 + i) = r.v;
}

// ---------------- stage 1: sanitize + NaN mask (transposed bf16) + gamma ----------------
// BigBT[c][n], c = b*128 + {f | 64+f}:  F0^T and M^T for the shift-GEMM.
// MT2[c][n],  c = b*64 + f:             M^T for the A2-GEMM.
__global__ __launch_bounds__(256) void stage1_kernel(
    const float* __restrict__ feat, const float* __restrict__ pi,
    const float* __restrict__ mu, const float* __restrict__ ivarr,
    bf16_t* __restrict__ BigBT, bf16_t* __restrict__ MT2, float* __restrict__ gamma) {
  __shared__ bf16_t F0s[64][72]; // +8 pad: column reads 2-way conflict only (free)
  __shared__ bf16_t Ms[64][72];
  int t = threadIdx.x;
  int b = blockIdx.x >> 6;
  int n0 = (blockIdx.x & 63) << 6;
  int r = t >> 2, c4 = t & 3; // row, 16-wide f chunk
  const float* frow = feat + ((size_t)b * NN + n0 + r) * FF + c4 * 16;

  float s[KK] = {0.f, 0.f, 0.f, 0.f, 0.f};
#pragma unroll
  for (int ch = 0; ch < 4; ++ch) {
    float4 v4 = *(const float4*)(frow + ch * 4);
    float vv[4] = {v4.x, v4.y, v4.z, v4.w};
#pragma unroll
    for (int e = 0; e < 4; ++e) {
      int f = c4 * 16 + ch * 4 + e;
      bool nb = is_nan(vv[e]);
      float x = nb ? 0.f : vv[e];
      F0s[r][f] = nb ? (bf16_t)0 : f2bf(x);
      Ms[r][f] = nb ? (bf16_t)0x3F80 : (bf16_t)0; // bf16(1.0)
#pragma unroll
      for (int k = 0; k < KK; ++k) {
        float d = nb ? 0.f : (x - mu[k * FF + f]);
        s[k] = fmaf(d * d, ivarr[k * FF + f], s[k]);
      }
    }
  }
  // reduce partial Mahalanobis over the 4 f-chunks (lane bits 0-1)
#pragma unroll
  for (int k = 0; k < KK; ++k) {
    s[k] += __shfl_xor(s[k], 1);
    s[k] += __shfl_xor(s[k], 2);
  }
  if (c4 == 0) {
    float l[KK], mx = -3.0e38f;
#pragma unroll
    for (int k = 0; k < KK; ++k) { l[k] = pi[k] - 0.5f * s[k]; mx = fmaxf(mx, l[k]); }
    float ek[KK], sum = 0.f;
#pragma unroll
    for (int k = 0; k < KK; ++k) { ek[k] = expf(l[k] - mx); sum += ek[k]; }
    float inv = 1.0f / sum;
#pragma unroll
    for (int k = 0; k < KK; ++k)
      gamma[((size_t)(b * KK + k)) * NN + n0 + r] = ek[k] * inv;
  }
  __syncthreads();
  // transposed stores: thread -> one f column, 16-row n chunk
  int f = t >> 2, nc = t & 3;
  union { bf16_t h[8]; uint4 v; } p;
#pragma unroll
  for (int half = 0; half < 2; ++half) {
    int nb8 = nc * 16 + half * 8;
#pragma unroll
    for (int e = 0; e < 8; ++e) p.h[e] = F0s[nb8 + e][f];
    *(uint4*)(BigBT + ((size_t)(b * 128 + f)) * NN + n0 + nb8) = p.v;
  }
#pragma unroll
  for (int half = 0; half < 2; ++half) {
    int nb8 = nc * 16 + half * 8;
#pragma unroll
    for (int e = 0; e < 8; ++e) p.h[e] = Ms[nb8 + e][f];
    *(uint4*)(BigBT + ((size_t)(b * 128 + 64 + f)) * NN + n0 + nb8) = p.v;
    *(uint4*)(MT2 + ((size_t)(b * 64 + f)) * NN + n0 + nb8) = p.v;
  }
}

// ---------------- big GEMM (m97 structure + XOR swizzle), bf16 out ----------------
// blocks [0,256):  QR = shift @ [F0|M]   (tile_c over 8 col-tiles, Cld=1024)
// blocks [256,384): P = A2 @ M           (tile_c over 4 col-tiles, Cld=512)
__global__ __launch_bounds__(256) void gemm_bt_kernel(
    const bf16_t* __restrict__ A0, const bf16_t* __restrict__ B0, bf16_t* __restrict__ C0,
    const bf16_t* __restrict__ A1, const bf16_t* __restrict__ B1, bf16_t* __restrict__ C1) {
  __shared__ bf16_t As[128 * 64];
  __shared__ bf16_t Bs[128 * 64];
  int bid = blockIdx.x;
  const bf16_t *A, *B;
  bf16_t* C;
  int tile_m, tile_c, Cld;
  if (bid < 256) {
    A = A0; B = B0; C = C0; tile_m = bid >> 3; tile_c = bid & 7; Cld = 1024;
  } else {
    int b2 = bid - 256;
    A = A1; B = B1; C = C1; tile_m = b2 >> 2; tile_c = b2 & 3; Cld = 512;
  }

  int tid = threadIdx.x;
  int wave = tid >> 6, lane = tid & 63;
  int wm = wave >> 1, wc = wave & 1;

  int srow = wave * 32 + (lane >> 3);
  int scol = (((lane & 7) ^ (lane >> 3)) << 3); // XOR-swizzled source chunk
  const bf16_t* Ag = A + (size_t)(tile_m * 128 + srow) * NN + scol;
  const bf16_t* Bg = B + (size_t)(tile_c * 128 + srow) * NN + scol;
  bf16_t* AsW = &As[(wave * 32) * 64];
  bf16_t* BsW = &Bs[(wave * 32) * 64];

  floatx4 acc[4][4];
#pragma unroll
  for (int i = 0; i < 4; ++i)
#pragma unroll
    for (int j = 0; j < 4; ++j) acc[i][j] = (floatx4){0.f, 0.f, 0.f, 0.f};

  int ml = lane & 15;
  int q = lane >> 4;
  int sw = ml & 7;

#pragma unroll 1
  for (int kt = 0; kt < 64; ++kt) {
    int k0 = kt * 64;
    __syncthreads();
#pragma unroll
    for (int i = 0; i < 4; ++i) {
      gld16(Ag + (size_t)(i * 8) * NN + k0, AsW + (i * 8) * 64);
      gld16(Bg + (size_t)(i * 8) * NN + k0, BsW + (i * 8) * 64);
    }
    __syncthreads();
#pragma unroll
    for (int ks = 0; ks < 2; ++ks) {
      int chunk = (((ks * 4 + q) ^ sw) << 3);
      short8 a[4], bb[4];
#pragma unroll
      for (int i = 0; i < 4; ++i)
        a[i] = *(const short8*)&As[(wm * 64 + i * 16 + ml) * 64 + chunk];
#pragma unroll
      for (int j = 0; j < 4; ++j)
        bb[j] = *(const short8*)&Bs[(wc * 64 + j * 16 + ml) * 64 + chunk];
#pragma unroll
      for (int i = 0; i < 4; ++i)
#pragma unroll
        for (int j = 0; j < 4; ++j)
          acc[i][j] = __builtin_amdgcn_mfma_f32_16x16x32_bf16(a[i], bb[j], acc[i][j], 0, 0, 0);
    }
  }

  int colb = tile_c * 128 + wc * 64 + ml;
#pragma unroll
  for (int i = 0; i < 4; ++i) {
    int mrow = tile_m * 128 + wm * 64 + i * 16 + q * 4;
#pragma unroll
    for (int j = 0; j < 4; ++j)
#pragma unroll
      for (int r = 0; r < 4; ++r)
        C[(size_t)(mrow + r) * Cld + colb + j * 16] = f2bf(acc[i][j][r]);
  }
}

// ---------------- stage 2: cx=QW+R@Ek, cc=P@Dk via MFMA; ex_relu*gamma k-sum; out ----------------
__global__ __launch_bounds__(256) void stage2_kernel(
    const bf16_t* __restrict__ QR, const bf16_t* __restrict__ P,
    const bf16_t* __restrict__ WTb, const bf16_t* __restrict__ EkT,
    const bf16_t* __restrict__ DkT, const float* __restrict__ gamma,
    float* __restrict__ out) {
  int t = threadIdx.x;
  int b = blockIdx.x >> 6;
  int n0 = (blockIdx.x & 63) << 6;
  int w = t >> 6, lane = t & 63, m = lane & 15, q = lane >> 4;
  int n = n0 + w * 16 + m;

  short8 Qf[2], Rf[2], Pf[2], wfr[4][2];
#pragma unroll
  for (int ks = 0; ks < 2; ++ks) {
    Qf[ks] = *(const short8*)(QR + (size_t)n * 1024 + b * 128 + ks * 32 + q * 8);
    Rf[ks] = *(const short8*)(QR + (size_t)n * 1024 + b * 128 + 64 + ks * 32 + q * 8);
    Pf[ks] = *(const short8*)(P + (size_t)n * 512 + b * 64 + ks * 32 + q * 8);
  }
#pragma unroll
  for (int ot = 0; ot < 4; ++ot)
#pragma unroll
    for (int ks = 0; ks < 2; ++ks)
      wfr[ot][ks] = *(const short8*)(WTb + (ot * 16 + m) * 64 + ks * 32 + q * 8);

  floatx4 z = (floatx4){0.f, 0.f, 0.f, 0.f};
  floatx4 QW[4], osum[4];
#pragma unroll
  for (int ot = 0; ot < 4; ++ot) {
    QW[ot] = __builtin_amdgcn_mfma_f32_16x16x32_bf16(Qf[0], wfr[ot][0], z, 0, 0, 0);
    QW[ot] = __builtin_amdgcn_mfma_f32_16x16x32_bf16(Qf[1], wfr[ot][1], QW[ot], 0, 0, 0);
    osum[ot] = z;
  }

#pragma unroll
  for (int k = 0; k < KK; ++k) {
    float4 g4 = *(const float4*)(gamma + ((size_t)(b * KK + k)) * NN + n0 + w * 16 + q * 4);
    float gg[4] = {g4.x, g4.y, g4.z, g4.w};
#pragma unroll
    for (int ot = 0; ot < 4; ++ot) {
      const bf16_t* ek = EkT + ((k * 64 + ot * 16 + m) * 64) + q * 8;
      const bf16_t* dk = DkT + ((k * 64 + ot * 16 + m) * 64) + q * 8;
      short8 e0 = *(const short8*)ek, e1 = *(const short8*)(ek + 32);
      short8 d0 = *(const short8*)dk, d1 = *(const short8*)(dk + 32);
      floatx4 cx4 = __builtin_amdgcn_mfma_f32_16x16x32_bf16(Rf[0], e0, QW[ot], 0, 0, 0);
      cx4 = __builtin_amdgcn_mfma_f32_16x16x32_bf16(Rf[1], e1, cx4, 0, 0, 0);
      floatx4 cc4 = __builtin_amdgcn_mfma_f32_16x16x32_bf16(Pf[0], d0, z, 0, 0, 0);
      cc4 = __builtin_amdgcn_mfma_f32_16x16x32_bf16(Pf[1], d1, cc4, 0, 0, 0);
#pragma unroll
      for (int r = 0; r < 4; ++r) {
        float mm = cx4[r];
        float v = cc4[r];
        float sd = sqrtf(fmaxf(v, 0.f));
        float zz = mm / (sd > 0.f ? sd : 1.f);
        float pdf = expf(-0.5f * zz * zz) * 0.3989422804014327f;
        float cdf = 0.5f * (1.f + erff(zz * 0.7071067811865476f));
        float ex = sd > 0.f ? fmaf(mm, cdf, sd * pdf) : fmaxf(mm, 0.f);
        osum[ot][r] = fmaf(gg[r], ex, osum[ot][r]);
      }
    }
  }

#pragma unroll
  for (int ot = 0; ot < 4; ++ot)
#pragma unroll
    for (int r = 0; r < 4; ++r)
      out[((size_t)b * NN + n0 + w * 16 + q * 4 + r) * OO + ot * 16 + m] = osum[ot][r];
}

extern "C" void kernel_launch(void* const* d_in, const int* in_sizes, int n_in,
                              void* d_out, int out_size, void* d_ws, size_t ws_size,
                              hipStream_t stream) {
  const float* shift = (const float*)d_in[0];
  const float* A2    = (const float*)d_in[1];
  const float* feat  = (const float*)d_in[2];
  const float* W     = (const float*)d_in[3];
  const float* pi    = (const float*)d_in[4];
  const float* mu    = (const float*)d_in[5];
  const float* sigma = (const float*)d_in[6];
  float* out = (float*)d_out;

  char* ws = (char*)d_ws;
  bf16_t* shift_bf = (bf16_t*)(ws + 0);         // 33,554,432
  bf16_t* A2_bf    = (bf16_t*)(ws + 33554432);  // 33,554,432
  bf16_t* BigBT    = (bf16_t*)(ws + 67108864);  //  8,388,608  [1024][4096]
  bf16_t* MT2      = (bf16_t*)(ws + 75497472);  //  4,194,304  [512][4096]
  bf16_t* QR       = (bf16_t*)(ws + 79691776);  //  8,388,608  [4096][1024]
  bf16_t* Pm       = (bf16_t*)(ws + 88080384);  //  4,194,304  [4096][512]
  float*  gam      = (float*) (ws + 92274688);  //    655,360  [B,K,N]
  float*  ivarr    = (float*) (ws + 92930048);  //      1,280
  bf16_t* WTb      = (bf16_t*)(ws + 92931328);  //      8,192
  bf16_t* EkT      = (bf16_t*)(ws + 92939520);  //     40,960
  bf16_t* DkT      = (bf16_t*)(ws + 92980480);  //     40,960  (end ~88.7 MiB)

  prep_kernel<<<80, 256, 0, stream>>>(W, sigma, mu, ivarr, WTb, EkT, DkT);
  cast2_kernel<<<8192, 256, 0, stream>>>(shift, A2, shift_bf, A2_bf);
  stage1_kernel<<<512, 256, 0, stream>>>(feat, pi, mu, ivarr, BigBT, MT2, gam);
  gemm_bt_kernel<<<384, 256, 0, stream>>>(shift_bf, BigBT, QR, A2_bf, MT2, Pm);
  stage2_kernel<<<512, 256, 0, stream>>>(QR, Pm, WTb, EkT, DkT, gam, out);
}

// Round 5
// 285.317 us; speedup vs baseline: 3.0961x; 1.0710x over previous
//
#include <hip/hip_runtime.h>

#define NN 4096
#define FF 64
#define OO 64
#define KK 5
#define BB 8

typedef unsigned short bf16_t;
typedef __attribute__((ext_vector_type(8))) short short8;
typedef __attribute__((ext_vector_type(4))) float floatx4;

__device__ __forceinline__ unsigned short f2bf(float x) {
  unsigned int u = __float_as_uint(x);
  return (unsigned short)((u + 0x7fffu + ((u >> 16) & 1u)) >> 16); // RNE
}
__device__ __forceinline__ float bf2f(unsigned short h) {
  return __uint_as_float(((unsigned int)h) << 16);
}
__device__ __forceinline__ bool is_nan(float x) {
  return (__float_as_uint(x) & 0x7fffffffu) > 0x7f800000u; // raw-bits, fast-math immune
}
__device__ __forceinline__ void gld16(const void* g, void* l) {
  __builtin_amdgcn_global_load_lds(
      (__attribute__((address_space(1))) const unsigned int*)g,
      (__attribute__((address_space(3))) unsigned int*)l, 16, 0, 0);
}

union S8 { short8 s; int4 i; uint4 u; };

// sum two bf16x8 fragments in f32, repack to bf16 (split-K reduce)
__device__ __forceinline__ short8 addbf(short8 x, short8 y) {
  S8 a, b, r;
  a.s = x; b.s = y;
#pragma unroll
  for (int e = 0; e < 8; ++e)
    r.s[e] = (short)f2bf(bf2f((unsigned short)a.s[e]) + bf2f((unsigned short)b.s[e]));
  return r.s;
}

// ---------------- prep: ivar + bf16 tables W^T, E_k^T=(mu.W)^T, D_k^T=(var.W^2)^T ----------------
__global__ __launch_bounds__(256) void prep_kernel(
    const float* __restrict__ W, const float* __restrict__ sigma, const float* __restrict__ mu,
    float* __restrict__ ivarr, bf16_t* __restrict__ WTb,
    bf16_t* __restrict__ EkT, bf16_t* __restrict__ DkT) {
  int t = blockIdx.x * 256 + threadIdx.x; // grid 80*256 = 20480 = K*64*64
  if (t < KK * FF) ivarr[t] = expf(-sigma[t]);
  if (t < FF * OO) {
    int o = t >> 6, f = t & 63;
    WTb[t] = f2bf(W[f * OO + o]);
  }
  int k = t >> 12, o = (t >> 6) & 63, f = t & 63;
  if (k < KK) {
    float w = W[f * OO + o];
    EkT[t] = f2bf(mu[k * FF + f] * w);
    DkT[t] = f2bf(expf(sigma[k * FF + f]) * w * w);
  }
}

// ---------------- f32 -> bf16 cast for both shift and A2 ----------------
__global__ __launch_bounds__(256) void cast2_kernel(
    const float* __restrict__ s0, const float* __restrict__ s1,
    bf16_t* __restrict__ d0, bf16_t* __restrict__ d1) {
  int i = (blockIdx.x * 256 + threadIdx.x) * 8;
  if (i + 8 > NN * NN) return;
  float4 a = *(const float4*)(s0 + i);
  float4 b = *(const float4*)(s0 + i + 4);
  union { unsigned short h[8]; uint4 v; } r;
  r.h[0] = f2bf(a.x); r.h[1] = f2bf(a.y); r.h[2] = f2bf(a.z); r.h[3] = f2bf(a.w);
  r.h[4] = f2bf(b.x); r.h[5] = f2bf(b.y); r.h[6] = f2bf(b.z); r.h[7] = f2bf(b.w);
  *(uint4*)(d0 + i) = r.v;
  a = *(const float4*)(s1 + i);
  b = *(const float4*)(s1 + i + 4);
  r.h[0] = f2bf(a.x); r.h[1] = f2bf(a.y); r.h[2] = f2bf(a.z); r.h[3] = f2bf(a.w);
  r.h[4] = f2bf(b.x); r.h[5] = f2bf(b.y); r.h[6] = f2bf(b.z); r.h[7] = f2bf(b.w);
  *(uint4*)(d1 + i) = r.v;
}

// ---------------- stage 1: sanitize + NaN mask (transposed bf16) + gamma ----------------
// BigBT[c][n], c = b*128 + {f | 64+f}: F0^T rows then M^T rows per batch.
// The A2-GEMM's B-panel aliases the M rows (no separate MT2 buffer).
__global__ __launch_bounds__(256) void stage1_kernel(
    const float* __restrict__ feat, const float* __restrict__ pi,
    const float* __restrict__ mu, const float* __restrict__ ivarr,
    bf16_t* __restrict__ BigBT, float* __restrict__ gamma) {
  __shared__ bf16_t F0s[64][66]; // pitch 66: nc-stride-8-row reads land on 4 banks x2 (cheap)
  __shared__ bf16_t Ms[64][66];
  int t = threadIdx.x;
  int b = blockIdx.x >> 6;
  int n0 = (blockIdx.x & 63) << 6;
  int r = t >> 2, c4 = t & 3; // row, 16-wide f chunk
  const float* frow = feat + ((size_t)b * NN + n0 + r) * FF + c4 * 16;

  float s[KK] = {0.f, 0.f, 0.f, 0.f, 0.f};
#pragma unroll
  for (int ch = 0; ch < 4; ++ch) {
    float4 v4 = *(const float4*)(frow + ch * 4);
    float vv[4] = {v4.x, v4.y, v4.z, v4.w};
#pragma unroll
    for (int e = 0; e < 4; ++e) {
      int f = c4 * 16 + ch * 4 + e;
      bool nb = is_nan(vv[e]);
      float x = nb ? 0.f : vv[e];
      F0s[r][f] = nb ? (bf16_t)0 : f2bf(x);
      Ms[r][f] = nb ? (bf16_t)0x3F80 : (bf16_t)0; // bf16(1.0)
#pragma unroll
      for (int k = 0; k < KK; ++k) {
        float d = nb ? 0.f : (x - mu[k * FF + f]);
        s[k] = fmaf(d * d, ivarr[k * FF + f], s[k]);
      }
    }
  }
#pragma unroll
  for (int k = 0; k < KK; ++k) {
    s[k] += __shfl_xor(s[k], 1);
    s[k] += __shfl_xor(s[k], 2);
  }
  if (c4 == 0) {
    float l[KK], mx = -3.0e38f;
#pragma unroll
    for (int k = 0; k < KK; ++k) { l[k] = pi[k] - 0.5f * s[k]; mx = fmaxf(mx, l[k]); }
    float ek[KK], sum = 0.f;
#pragma unroll
    for (int k = 0; k < KK; ++k) { ek[k] = expf(l[k] - mx); sum += ek[k]; }
    float inv = 1.0f / sum;
#pragma unroll
    for (int k = 0; k < KK; ++k)
      gamma[((size_t)(b * KK + k)) * NN + n0 + r] = ek[k] * inv;
  }
  __syncthreads();
  // transposed stores: lane&7 -> 8-elem n chunk (fast axis), lane>>3 -> f row.
  // Each 8-lane group writes one contiguous 128B run; wave = 8 f-rows.
#pragma unroll
  for (int it = 0; it < 2; ++it) {
    int f = it * 32 + (t >> 3);
    int nc = t & 7;
    union { bf16_t h[8]; uint4 v; } p;
#pragma unroll
    for (int e = 0; e < 8; ++e) p.h[e] = F0s[nc * 8 + e][f];
    *(uint4*)(BigBT + ((size_t)(b * 128 + f)) * NN + n0 + nc * 8) = p.v;
#pragma unroll
    for (int e = 0; e < 8; ++e) p.h[e] = Ms[nc * 8 + e][f];
    *(uint4*)(BigBT + ((size_t)(b * 128 + 64 + f)) * NN + n0 + nc * 8) = p.v;
  }
}

// ---------------- big GEMM, split-K x2 (m97 structure + XOR swizzle), bf16 partials ----------------
// blocks [0,512):   QRp[kh] = shift @ [F0|M]_half   (tile_m 32, tile_c 8, kh 2)
// blocks [512,768): Pp[kh]  = A2 @ M_half           (tile_m 32, tile_c 4, kh 2)
// 768 blocks = exactly 3 per CU.
__global__ __launch_bounds__(256) void gemm_bt_kernel(
    const bf16_t* __restrict__ A0, const bf16_t* __restrict__ BigBT, bf16_t* __restrict__ C0,
    const bf16_t* __restrict__ A1, bf16_t* __restrict__ C1) {
  __shared__ bf16_t As[128 * 64];
  __shared__ bf16_t Bs[128 * 64];
  int bid = blockIdx.x;
  const bf16_t* A;
  bf16_t* C;
  int tile_m, tile_c, kh, Cld;
  bool isP;
  if (bid < 512) {
    isP = false; A = A0;
    kh = bid & 1; int tmp = bid >> 1;
    tile_m = tmp >> 3; tile_c = tmp & 7; Cld = 1024;
    C = C0 + (size_t)kh * (NN * 1024);
  } else {
    isP = true; A = A1;
    int b2 = bid - 512;
    kh = b2 & 1; int tmp = b2 >> 1;
    tile_m = tmp >> 2; tile_c = tmp & 3; Cld = 512;
    C = C1 + (size_t)kh * (NN * 512);
  }

  int tid = threadIdx.x;
  int wave = tid >> 6, lane = tid & 63;
  int wm = wave >> 1, wc = wave & 1;

  int srow = wave * 32 + (lane >> 3);
  int scol = (((lane & 7) ^ (lane >> 3)) << 3); // XOR-swizzled source chunk
  const bf16_t* Ag = A + (size_t)(tile_m * 128 + srow) * NN + scol;
  int browi;
  if (!isP) {
    browi = tile_c * 128 + srow;
  } else {
    int c2 = tile_c * 128 + srow; // P's B row c2 = b*64+f -> BigBT M row b*128+64+f
    browi = ((c2 >> 6) << 7) + 64 + (c2 & 63);
  }
  const bf16_t* Bg = BigBT + (size_t)browi * NN + scol;
  bf16_t* AsW = &As[(wave * 32) * 64];
  bf16_t* BsW = &Bs[(wave * 32) * 64];

  floatx4 acc[4][4];
#pragma unroll
  for (int i = 0; i < 4; ++i)
#pragma unroll
    for (int j = 0; j < 4; ++j) acc[i][j] = (floatx4){0.f, 0.f, 0.f, 0.f};

  int ml = lane & 15;
  int q = lane >> 4;
  int sw = ml & 7;

#pragma unroll 1
  for (int kt = kh * 32; kt < kh * 32 + 32; ++kt) {
    int k0 = kt * 64;
    __syncthreads();
#pragma unroll
    for (int i = 0; i < 4; ++i) {
      gld16(Ag + (size_t)(i * 8) * NN + k0, AsW + (i * 8) * 64);
      gld16(Bg + (size_t)(i * 8) * NN + k0, BsW + (i * 8) * 64);
    }
    __syncthreads();
#pragma unroll
    for (int ks = 0; ks < 2; ++ks) {
      int chunk = (((ks * 4 + q) ^ sw) << 3);
      short8 a[4], bb[4];
#pragma unroll
      for (int i = 0; i < 4; ++i)
        a[i] = *(const short8*)&As[(wm * 64 + i * 16 + ml) * 64 + chunk];
#pragma unroll
      for (int j = 0; j < 4; ++j)
        bb[j] = *(const short8*)&Bs[(wc * 64 + j * 16 + ml) * 64 + chunk];
#pragma unroll
      for (int i = 0; i < 4; ++i)
#pragma unroll
        for (int j = 0; j < 4; ++j)
          acc[i][j] = __builtin_amdgcn_mfma_f32_16x16x32_bf16(a[i], bb[j], acc[i][j], 0, 0, 0);
    }
  }

  int colb = tile_c * 128 + wc * 64 + ml;
#pragma unroll
  for (int i = 0; i < 4; ++i) {
    int mrow = tile_m * 128 + wm * 64 + i * 16 + q * 4;
#pragma unroll
    for (int j = 0; j < 4; ++j)
#pragma unroll
      for (int r = 0; r < 4; ++r)
        C[(size_t)(mrow + r) * Cld + colb + j * 16] = f2bf(acc[i][j][r]);
  }
}

// ---------------- stage 2: split-K reduce; cx=QW+R@Ek, cc=P@Dk; ex_relu*gamma k-sum ----------------
__global__ __launch_bounds__(256) void stage2_kernel(
    const bf16_t* __restrict__ QRp, const bf16_t* __restrict__ Pp,
    const bf16_t* __restrict__ WTb, const bf16_t* __restrict__ EkT,
    const bf16_t* __restrict__ DkT, const float* __restrict__ gamma,
    float* __restrict__ out) {
  const bf16_t* QR1 = QRp + (size_t)NN * 1024;
  const bf16_t* Pp1 = Pp + (size_t)NN * 512;
  int t = threadIdx.x;
  int b = blockIdx.x >> 6;
  int n0 = (blockIdx.x & 63) << 6;
  int w = t >> 6, lane = t & 63, m = lane & 15, q = lane >> 4;
  int n = n0 + w * 16 + m;

  short8 Qf[2], Rf[2], Pf[2], wfr[4][2];
#pragma unroll
  for (int ks = 0; ks < 2; ++ks) {
    size_t oq = (size_t)n * 1024 + b * 128 + ks * 32 + q * 8;
    size_t op = (size_t)n * 512 + b * 64 + ks * 32 + q * 8;
    Qf[ks] = addbf(*(const short8*)(QRp + oq), *(const short8*)(QR1 + oq));
    Rf[ks] = addbf(*(const short8*)(QRp + oq + 64), *(const short8*)(QR1 + oq + 64));
    Pf[ks] = addbf(*(const short8*)(Pp + op), *(const short8*)(Pp1 + op));
  }
#pragma unroll
  for (int ot = 0; ot < 4; ++ot)
#pragma unroll
    for (int ks = 0; ks < 2; ++ks)
      wfr[ot][ks] = *(const short8*)(WTb + (ot * 16 + m) * 64 + ks * 32 + q * 8);

  floatx4 z = (floatx4){0.f, 0.f, 0.f, 0.f};
  floatx4 QW[4], osum[4];
#pragma unroll
  for (int ot = 0; ot < 4; ++ot) {
    QW[ot] = __builtin_amdgcn_mfma_f32_16x16x32_bf16(Qf[0], wfr[ot][0], z, 0, 0, 0);
    QW[ot] = __builtin_amdgcn_mfma_f32_16x16x32_bf16(Qf[1], wfr[ot][1], QW[ot], 0, 0, 0);
    osum[ot] = z;
  }

#pragma unroll
  for (int k = 0; k < KK; ++k) {
    float4 g4 = *(const float4*)(gamma + ((size_t)(b * KK + k)) * NN + n0 + w * 16 + q * 4);
    float gg[4] = {g4.x, g4.y, g4.z, g4.w};
#pragma unroll
    for (int ot = 0; ot < 4; ++ot) {
      const bf16_t* ek = EkT + ((k * 64 + ot * 16 + m) * 64) + q * 8;
      const bf16_t* dk = DkT + ((k * 64 + ot * 16 + m) * 64) + q * 8;
      short8 e0 = *(const short8*)ek, e1 = *(const short8*)(ek + 32);
      short8 d0 = *(const short8*)dk, d1 = *(const short8*)(dk + 32);
      floatx4 cx4 = __builtin_amdgcn_mfma_f32_16x16x32_bf16(Rf[0], e0, QW[ot], 0, 0, 0);
      cx4 = __builtin_amdgcn_mfma_f32_16x16x32_bf16(Rf[1], e1, cx4, 0, 0, 0);
      floatx4 cc4 = __builtin_amdgcn_mfma_f32_16x16x32_bf16(Pf[0], d0, z, 0, 0, 0);
      cc4 = __builtin_amdgcn_mfma_f32_16x16x32_bf16(Pf[1], d1, cc4, 0, 0, 0);
#pragma unroll
      for (int r = 0; r < 4; ++r) {
        float mm = cx4[r];
        float v = cc4[r];
        float sd = sqrtf(fmaxf(v, 0.f));
        float zz = mm / (sd > 0.f ? sd : 1.f);
        float pdf = expf(-0.5f * zz * zz) * 0.3989422804014327f;
        float cdf = 0.5f * (1.f + erff(zz * 0.7071067811865476f));
        float ex = sd > 0.f ? fmaf(mm, cdf, sd * pdf) : fmaxf(mm, 0.f);
        osum[ot][r] = fmaf(gg[r], ex, osum[ot][r]);
      }
    }
  }

#pragma unroll
  for (int ot = 0; ot < 4; ++ot)
#pragma unroll
    for (int r = 0; r < 4; ++r)
      out[((size_t)b * NN + n0 + w * 16 + q * 4 + r) * OO + ot * 16 + m] = osum[ot][r];
}

extern "C" void kernel_launch(void* const* d_in, const int* in_sizes, int n_in,
                              void* d_out, int out_size, void* d_ws, size_t ws_size,
                              hipStream_t stream) {
  const float* shift = (const float*)d_in[0];
  const float* A2    = (const float*)d_in[1];
  const float* feat  = (const float*)d_in[2];
  const float* W     = (const float*)d_in[3];
  const float* pi    = (const float*)d_in[4];
  const float* mu    = (const float*)d_in[5];
  const float* sigma = (const float*)d_in[6];
  float* out = (float*)d_out;

  char* ws = (char*)d_ws;
  bf16_t* shift_bf = (bf16_t*)(ws + 0);          // 33,554,432
  bf16_t* A2_bf    = (bf16_t*)(ws + 33554432);   // 33,554,432
  bf16_t* BigBT    = (bf16_t*)(ws + 67108864);   //  8,388,608  [1024][4096]
  bf16_t* QRp      = (bf16_t*)(ws + 75497472);   // 16,777,216  [2][4096][1024]
  bf16_t* Pp       = (bf16_t*)(ws + 92274688);   //  8,388,608  [2][4096][512]
  float*  gam      = (float*) (ws + 100663296);  //    655,360  [B,K,N]
  float*  ivarr    = (float*) (ws + 101318656);  //      1,280
  bf16_t* WTb      = (bf16_t*)(ws + 101319936);  //      8,192
  bf16_t* EkT      = (bf16_t*)(ws + 101328128);  //     40,960
  bf16_t* DkT      = (bf16_t*)(ws + 101369088);  //     40,960  (end ~96.7 MiB)

  prep_kernel<<<80, 256, 0, stream>>>(W, sigma, mu, ivarr, WTb, EkT, DkT);
  cast2_kernel<<<8192, 256, 0, stream>>>(shift, A2, shift_bf, A2_bf);
  stage1_kernel<<<512, 256, 0, stream>>>(feat, pi, mu, ivarr, BigBT, gam);
  gemm_bt_kernel<<<768, 256, 0, stream>>>(shift_bf, BigBT, QRp, A2_bf, Pp);
  stage2_kernel<<<512, 256, 0, stream>>>(QRp, Pp, WTb, EkT, DkT, gam, out);
}